// Round 1
// baseline (945.807 us; speedup 1.0000x reference)
//
#include <hip/hip_runtime.h>
#include <stdint.h>

typedef unsigned short u16;
typedef __bf16 bf16x8 __attribute__((ext_vector_type(8)));
typedef float f32x4 __attribute__((ext_vector_type(4)));

#define DEV __device__ __forceinline__

DEV float bf2f(u16 u) {
    union { uint32_t u; float f; } c; c.u = ((uint32_t)u) << 16; return c.f;
}
DEV u16 f2bf(float f) {
    union { float f; uint32_t u; } c; c.f = f;
    uint32_t u = c.u;
    u += 0x7FFFu + ((u >> 16) & 1u);   // round-to-nearest-even
    return (u16)(u >> 16);
}

DEV void gload_lds16(const u16* gp, u16* lp) {
    __builtin_amdgcn_global_load_lds(
        (__attribute__((address_space(1))) u16*)(uintptr_t)gp,
        (__attribute__((address_space(3))) u16*)lp,
        16, 0, 0);
}

// ---------------------------------------------------------------- convert
__global__ __launch_bounds__(256) void k_f32_to_bf16(
    const float* __restrict__ in, u16* __restrict__ out, int n4)
{
    int i = blockIdx.x * 256 + threadIdx.x;
    if (i >= n4) return;
    float4 v = reinterpret_cast<const float4*>(in)[i];
    ushort4 o;
    o.x = f2bf(v.x); o.y = f2bf(v.y); o.z = f2bf(v.z); o.w = f2bf(v.w);
    reinterpret_cast<ushort4*>(out)[i] = o;
}

// ---------------------------------------------------------------- GEMM
// C[M,N] = A[M,K] * W[N,K]^T + bias (+ residual) (+relu), all bf16 in, bf16 out.
// 128x128 tile, 4 waves (2x2), each wave 64x64 via 4x4 MFMA 16x16x32 frags.
template<bool RELU, bool RESID>
__global__ __launch_bounds__(256) void k_gemm(
    const u16* __restrict__ A, const u16* __restrict__ W,
    const float* __restrict__ bias, const u16* __restrict__ res,
    u16* __restrict__ C, int M, int N, int K)
{
    __shared__ __align__(16) u16 As[128 * 32];
    __shared__ __align__(16) u16 Bs[128 * 32];

    const int tid  = threadIdx.x;
    const int lane = tid & 63;
    const int wave = tid >> 6;
    const int wm   = wave >> 1;
    const int wn   = wave & 1;
    const long tileM = (long)blockIdx.y * 128;
    const long tileN = (long)blockIdx.x * 128;

    f32x4 acc[4][4] = {};

    // staging geometry: chunk = tid covers 16B; row = tid>>2, k-chunk = tid&3
    const int r4 = tid >> 2;
    const int c8 = (tid & 3) * 8;
    const u16* Ab = A + (tileM + r4) * (long)K + c8;
    const u16* Wb = W + (tileN + r4) * (long)K + c8;
    u16* ldsA0 = As + wave * 512;          // bytes: wave*1024
    u16* ldsA1 = As + 2048 + wave * 512;   // second 64 rows
    u16* ldsB0 = Bs + wave * 512;
    u16* ldsB1 = Bs + 2048 + wave * 512;

    const int arow = wm * 64 + (lane & 15);
    const int brow = wn * 64 + (lane & 15);
    const int kc   = (lane >> 4) * 8;

    for (int kk = 0; kk < K; kk += 32) {
        gload_lds16(Ab + kk,                 ldsA0);
        gload_lds16(Ab + kk + (long)64 * K,  ldsA1);
        gload_lds16(Wb + kk,                 ldsB0);
        gload_lds16(Wb + kk + (long)64 * K,  ldsB1);
        __syncthreads();

        bf16x8 a[4], b[4];
#pragma unroll
        for (int f = 0; f < 4; ++f) {
            a[f] = *reinterpret_cast<const bf16x8*>(&As[(arow + f * 16) * 32 + kc]);
            b[f] = *reinterpret_cast<const bf16x8*>(&Bs[(brow + f * 16) * 32 + kc]);
        }
#pragma unroll
        for (int i = 0; i < 4; ++i)
#pragma unroll
            for (int j = 0; j < 4; ++j)
                acc[i][j] = __builtin_amdgcn_mfma_f32_16x16x32_bf16(
                    a[i], b[j], acc[i][j], 0, 0, 0);
        __syncthreads();
    }

    // epilogue: C/D layout col = lane&15, row = (lane>>4)*4 + reg
    const int crow = (int)tileM + wm * 64 + ((lane >> 4) << 2);
    const int ccol = (int)tileN + wn * 64 + (lane & 15);
#pragma unroll
    for (int i = 0; i < 4; ++i) {
#pragma unroll
        for (int j = 0; j < 4; ++j) {
            const int col = ccol + j * 16;
            const float bv = bias[col];
#pragma unroll
            for (int r = 0; r < 4; ++r) {
                const long row = crow + i * 16 + r;
                float v = acc[i][j][r] + bv;
                if (RESID) v += bf2f(res[row * N + col]);
                if (RELU)  v = fmaxf(v, 0.0f);
                C[row * N + col] = f2bf(v);
            }
        }
    }
}

// ---------------------------------------------------------------- attention
// block = 512 threads = 8 waves = 8 heads; lane = head-dim (DH = 64).
// MODE 0: station attn, groups (b,f,t), L=2,  row stride 312 (=NF*T)
// MODE 1: feature attn, groups (b,s,t), L=13, row stride 24  (=T)
template<int L, int MODE>
__global__ __launch_bounds__(512) void k_attn(
    const u16* __restrict__ qkv, u16* __restrict__ o)
{
    const int g = blockIdx.x;
    const int h = threadIdx.x >> 6;
    const int d = threadIdx.x & 63;
    int base, stride;
    if (MODE == 0) {
        const int t = g % 24, bf = g / 24, f = bf % 13, b = bf / 13;
        base = b * 624 + f * 24 + t; stride = 312;
    } else {
        const int t = g % 24, bs = g / 24, s = bs % 2, b = bs / 2;
        base = b * 624 + s * 312 + t; stride = 24;
    }

    float q[L], k[L], v[L];
#pragma unroll
    for (int j = 0; j < L; ++j) {
        const u16* p = qkv + (size_t)(base + j * stride) * 1536 + h * 64 + d;
        q[j] = bf2f(p[0]);
        k[j] = bf2f(p[512]);
        v[j] = bf2f(p[1024]);
    }

#pragma unroll
    for (int i = 0; i < L; ++i) {
        float sc[L];
#pragma unroll
        for (int j = 0; j < L; ++j) {
            float t2 = q[i] * k[j];
#pragma unroll
            for (int off = 32; off; off >>= 1) t2 += __shfl_xor(t2, off);
            sc[j] = t2 * 0.125f;   // 1/sqrt(64)
        }
        float m = sc[0];
#pragma unroll
        for (int j = 1; j < L; ++j) m = fmaxf(m, sc[j]);
        float den = 0.0f;
#pragma unroll
        for (int j = 0; j < L; ++j) { sc[j] = expf(sc[j] - m); den += sc[j]; }
        const float inv = 1.0f / den;
        float ov = 0.0f;
#pragma unroll
        for (int j = 0; j < L; ++j) ov += sc[j] * v[j];
        ov *= inv;
        o[(size_t)(base + i * stride) * 512 + h * 64 + d] = f2bf(ov);
    }
}

// ---------------------------------------------------------------- layernorm
// wave per row (512 = 64 lanes * 8). In-place capable (read row then write row).
template<bool OUTF32>
__global__ __launch_bounds__(256) void k_ln(
    const u16* __restrict__ in, const float* __restrict__ g,
    const float* __restrict__ be, u16* __restrict__ outb,
    float* __restrict__ outf)
{
    const int row  = blockIdx.x * 4 + (threadIdx.x >> 6);
    const int lane = threadIdx.x & 63;
    const u16* p = in + (size_t)row * 512 + lane * 8;

    uint4 va = *reinterpret_cast<const uint4*>(p);
    uint32_t ua[4] = { va.x, va.y, va.z, va.w };
    float x[8];
#pragma unroll
    for (int i = 0; i < 4; ++i) {
        x[2 * i]     = bf2f((u16)(ua[i] & 0xFFFFu));
        x[2 * i + 1] = bf2f((u16)(ua[i] >> 16));
    }
    float s = 0.f, sq = 0.f;
#pragma unroll
    for (int i = 0; i < 8; ++i) { s += x[i]; sq += x[i] * x[i]; }
#pragma unroll
    for (int off = 32; off; off >>= 1) {
        s  += __shfl_xor(s, off);
        sq += __shfl_xor(sq, off);
    }
    const float mean = s * (1.0f / 512.0f);
    const float var  = sq * (1.0f / 512.0f) - mean * mean;
    const float rstd = rsqrtf(var + 1e-5f);

    const int col = lane * 8;
    float4 g0 = *reinterpret_cast<const float4*>(g + col);
    float4 g1 = *reinterpret_cast<const float4*>(g + col + 4);
    float4 b0 = *reinterpret_cast<const float4*>(be + col);
    float4 b1 = *reinterpret_cast<const float4*>(be + col + 4);
    float gg[8] = { g0.x, g0.y, g0.z, g0.w, g1.x, g1.y, g1.z, g1.w };
    float bb[8] = { b0.x, b0.y, b0.z, b0.w, b1.x, b1.y, b1.z, b1.w };

    float y[8];
#pragma unroll
    for (int i = 0; i < 8; ++i) y[i] = (x[i] - mean) * rstd * gg[i] + bb[i];

    if (OUTF32) {
        float4 o0 = { y[0], y[1], y[2], y[3] };
        float4 o1 = { y[4], y[5], y[6], y[7] };
        reinterpret_cast<float4*>(outf + (size_t)row * 512 + col)[0] = o0;
        reinterpret_cast<float4*>(outf + (size_t)row * 512 + col + 4)[0] = o1;
    } else {
        uint32_t w[4];
#pragma unroll
        for (int i = 0; i < 4; ++i)
            w[i] = (uint32_t)f2bf(y[2 * i]) | ((uint32_t)f2bf(y[2 * i + 1]) << 16);
        uint4 ov = { w[0], w[1], w[2], w[3] };
        *reinterpret_cast<uint4*>(outb + (size_t)row * 512 + col) = ov;
    }
}

// ---------------------------------------------------------------- launch
extern "C" void kernel_launch(void* const* d_in, const int* in_sizes, int n_in,
                              void* d_out, int out_size, void* d_ws, size_t ws_size,
                              hipStream_t stream)
{
    const float* x       = (const float*)d_in[0];
    const float* w_in_s  = (const float*)d_in[1];
    const float* b_in_s  = (const float*)d_in[2];
    const float* w_out_s = (const float*)d_in[3];
    const float* b_out_s = (const float*)d_in[4];
    const float* w_in_f  = (const float*)d_in[5];
    const float* b_in_f  = (const float*)d_in[6];
    const float* w_out_f = (const float*)d_in[7];
    const float* b_out_f = (const float*)d_in[8];
    const float* w1      = (const float*)d_in[9];
    const float* b1      = (const float*)d_in[10];
    const float* w2      = (const float*)d_in[11];
    const float* b2      = (const float*)d_in[12];
    const float* g1      = (const float*)d_in[13];
    const float* be1     = (const float*)d_in[14];
    const float* g2      = (const float*)d_in[15];
    const float* be2     = (const float*)d_in[16];
    const float* g3      = (const float*)d_in[17];
    const float* be3     = (const float*)d_in[18];

    const int R = 39936;               // B*NS*NF*T = 64*2*13*24
    u16* xb   = (u16*)d_ws;            // [R,512]  activation (bf16)
    u16* buf1 = xb + (size_t)R * 512;  // [R,2048] qkv(1536)+o(512) / ffn hidden
    u16* obuf = buf1 + (size_t)R * 1536;
    u16* wqs  = buf1 + (size_t)R * 2048;
    u16* wos  = wqs + 1536 * 512;
    u16* wqf  = wos + 512 * 512;
    u16* wof  = wqf + 1536 * 512;
    u16* w1b  = wof + 512 * 512;
    u16* w2b  = w1b + 2048 * 512;

    auto conv = [&](const float* src, u16* dst, int n) {
        int n4 = n / 4;
        k_f32_to_bf16<<<dim3((n4 + 255) / 256), dim3(256), 0, stream>>>(src, dst, n4);
    };
    conv(x,       xb,  R * 512);
    conv(w_in_s,  wqs, 1536 * 512);
    conv(w_out_s, wos, 512 * 512);
    conv(w_in_f,  wqf, 1536 * 512);
    conv(w_out_f, wof, 512 * 512);
    conv(w1,      w1b, 2048 * 512);
    conv(w2,      w2b, 512 * 2048);

    const dim3 blk(256);
    const int MT = R / 128;   // 312 row tiles

    // ---- station attention block ----
    k_gemm<false, false><<<dim3(12, MT), blk, 0, stream>>>(
        xb, wqs, b_in_s, nullptr, buf1, R, 1536, 512);
    k_attn<2, 0><<<dim3(64 * 13 * 24), dim3(512), 0, stream>>>(buf1, obuf);
    k_gemm<false, true><<<dim3(4, MT), blk, 0, stream>>>(
        obuf, wos, b_out_s, xb, xb, R, 512, 512);        // + residual, in place
    k_ln<false><<<dim3(R / 4), dim3(256), 0, stream>>>(xb, g1, be1, xb, nullptr);

    // ---- feature attention block ----
    k_gemm<false, false><<<dim3(12, MT), blk, 0, stream>>>(
        xb, wqf, b_in_f, nullptr, buf1, R, 1536, 512);
    k_attn<13, 1><<<dim3(64 * 2 * 24), dim3(512), 0, stream>>>(buf1, obuf);
    k_gemm<false, true><<<dim3(4, MT), blk, 0, stream>>>(
        obuf, wof, b_out_f, xb, xb, R, 512, 512);
    k_ln<false><<<dim3(R / 4), dim3(256), 0, stream>>>(xb, g2, be2, xb, nullptr);

    // ---- feed-forward ----
    k_gemm<true, false><<<dim3(16, MT), blk, 0, stream>>>(
        xb, w1b, b1, nullptr, buf1, R, 2048, 512);
    k_gemm<false, true><<<dim3(4, MT), blk, 0, stream>>>(
        buf1, w2b, b2, xb, xb, R, 512, 2048);
    k_ln<true><<<dim3(R / 4), dim3(256), 0, stream>>>(xb, g3, be3, nullptr, (float*)d_out);
}

// Round 2
// 736.994 us; speedup vs baseline: 1.2833x; 1.2833x over previous
//
#include <hip/hip_runtime.h>
#include <stdint.h>

typedef unsigned short u16;
typedef __bf16 bf16x8 __attribute__((ext_vector_type(8)));
typedef float f32x4 __attribute__((ext_vector_type(4)));

#define DEV __device__ __forceinline__

DEV float bf2f(u16 u) {
    union { uint32_t u; float f; } c; c.u = ((uint32_t)u) << 16; return c.f;
}
DEV u16 f2bf(float f) {
    union { float f; uint32_t u; } c; c.f = f;
    uint32_t u = c.u;
    u += 0x7FFFu + ((u >> 16) & 1u);   // round-to-nearest-even
    return (u16)(u >> 16);
}

DEV void gload_lds16(const u16* gp, u16* lp) {
    __builtin_amdgcn_global_load_lds(
        (__attribute__((address_space(1))) u16*)(uintptr_t)gp,
        (__attribute__((address_space(3))) u16*)lp,
        16, 0, 0);
}

// ---- 16-bf16 (32B) helpers -------------------------------------------------
DEV void load16f(const u16* p, float* f) {
    uint4 a = *reinterpret_cast<const uint4*>(p);
    uint4 b = *reinterpret_cast<const uint4*>(p + 8);
    uint32_t w[8] = { a.x, a.y, a.z, a.w, b.x, b.y, b.z, b.w };
#pragma unroll
    for (int k = 0; k < 8; ++k) {
        union { uint32_t u; float f; } lo, hi;
        lo.u = w[k] << 16; hi.u = w[k] & 0xFFFF0000u;
        f[2 * k] = lo.f; f[2 * k + 1] = hi.f;
    }
}
DEV float dot16(const u16* p, const float* q) {
    uint4 a = *reinterpret_cast<const uint4*>(p);
    uint4 b = *reinterpret_cast<const uint4*>(p + 8);
    uint32_t w[8] = { a.x, a.y, a.z, a.w, b.x, b.y, b.z, b.w };
    float d = 0.0f;
#pragma unroll
    for (int k = 0; k < 8; ++k) {
        union { uint32_t u; float f; } lo, hi;
        lo.u = w[k] << 16; hi.u = w[k] & 0xFFFF0000u;
        d += q[2 * k] * lo.f;
        d += q[2 * k + 1] * hi.f;
    }
    return d;
}
DEV void fma16(const u16* p, float pw, float* acc) {
    uint4 a = *reinterpret_cast<const uint4*>(p);
    uint4 b = *reinterpret_cast<const uint4*>(p + 8);
    uint32_t w[8] = { a.x, a.y, a.z, a.w, b.x, b.y, b.z, b.w };
#pragma unroll
    for (int k = 0; k < 8; ++k) {
        union { uint32_t u; float f; } lo, hi;
        lo.u = w[k] << 16; hi.u = w[k] & 0xFFFF0000u;
        acc[2 * k] += pw * lo.f;
        acc[2 * k + 1] += pw * hi.f;
    }
}
DEV void store16(u16* p, const float* y) {
    uint32_t w[8];
#pragma unroll
    for (int k = 0; k < 8; ++k)
        w[k] = (uint32_t)f2bf(y[2 * k]) | ((uint32_t)f2bf(y[2 * k + 1]) << 16);
    uint4 a = { w[0], w[1], w[2], w[3] };
    uint4 b = { w[4], w[5], w[6], w[7] };
    *reinterpret_cast<uint4*>(p) = a;
    *reinterpret_cast<uint4*>(p + 8) = b;
}

// ---------------------------------------------------------------- convert
__global__ __launch_bounds__(256) void k_f32_to_bf16(
    const float* __restrict__ in, u16* __restrict__ out, int n4)
{
    int i = blockIdx.x * 256 + threadIdx.x;
    if (i >= n4) return;
    float4 v = reinterpret_cast<const float4*>(in)[i];
    ushort4 o;
    o.x = f2bf(v.x); o.y = f2bf(v.y); o.z = f2bf(v.z); o.w = f2bf(v.w);
    reinterpret_cast<ushort4*>(out)[i] = o;
}

// ---------------------------------------------------------------- GEMM
// C[M,N] = A[M,K] * W[N,K]^T + bias (+ residual) (+relu), all bf16 in, bf16 out.
template<bool RELU, bool RESID>
__global__ __launch_bounds__(256) void k_gemm(
    const u16* __restrict__ A, const u16* __restrict__ W,
    const float* __restrict__ bias, const u16* __restrict__ res,
    u16* __restrict__ C, int M, int N, int K)
{
    __shared__ __align__(16) u16 As[128 * 32];
    __shared__ __align__(16) u16 Bs[128 * 32];

    const int tid  = threadIdx.x;
    const int lane = tid & 63;
    const int wave = tid >> 6;
    const int wm   = wave >> 1;
    const int wn   = wave & 1;
    const long tileM = (long)blockIdx.y * 128;
    const long tileN = (long)blockIdx.x * 128;

    f32x4 acc[4][4] = {};

    const int r4 = tid >> 2;
    const int c8 = (tid & 3) * 8;
    const u16* Ab = A + (tileM + r4) * (long)K + c8;
    const u16* Wb = W + (tileN + r4) * (long)K + c8;
    u16* ldsA0 = As + wave * 512;
    u16* ldsA1 = As + 2048 + wave * 512;
    u16* ldsB0 = Bs + wave * 512;
    u16* ldsB1 = Bs + 2048 + wave * 512;

    const int arow = wm * 64 + (lane & 15);
    const int brow = wn * 64 + (lane & 15);
    const int kc   = (lane >> 4) * 8;

    for (int kk = 0; kk < K; kk += 32) {
        gload_lds16(Ab + kk,                 ldsA0);
        gload_lds16(Ab + kk + (long)64 * K,  ldsA1);
        gload_lds16(Wb + kk,                 ldsB0);
        gload_lds16(Wb + kk + (long)64 * K,  ldsB1);
        __syncthreads();

        bf16x8 a[4], b[4];
#pragma unroll
        for (int f = 0; f < 4; ++f) {
            a[f] = *reinterpret_cast<const bf16x8*>(&As[(arow + f * 16) * 32 + kc]);
            b[f] = *reinterpret_cast<const bf16x8*>(&Bs[(brow + f * 16) * 32 + kc]);
        }
#pragma unroll
        for (int i = 0; i < 4; ++i)
#pragma unroll
            for (int j = 0; j < 4; ++j)
                acc[i][j] = __builtin_amdgcn_mfma_f32_16x16x32_bf16(
                    a[i], b[j], acc[i][j], 0, 0, 0);
        __syncthreads();
    }

    const int crow = (int)tileM + wm * 64 + ((lane >> 4) << 2);
    const int ccol = (int)tileN + wn * 64 + (lane & 15);
#pragma unroll
    for (int i = 0; i < 4; ++i) {
#pragma unroll
        for (int j = 0; j < 4; ++j) {
            const int col = ccol + j * 16;
            const float bv = bias[col];
#pragma unroll
            for (int r = 0; r < 4; ++r) {
                const long row = crow + i * 16 + r;
                float v = acc[i][j][r] + bv;
                if (RESID) v += bf2f(res[row * N + col]);
                if (RELU)  v = fmaxf(v, 0.0f);
                C[row * N + col] = f2bf(v);
            }
        }
    }
}

// ---------------------------------------------------------------- attention
// Station attn (L=2): one wave per group g=(b,f,t), all 8 heads.
// lane = h*8 + i*4 + c : h=head, i=output row (0..1), c=16-dim chunk (0..3).
// Quad (c=0..3) reduces the 64-dim dot with two DPP shuffles; softmax in-lane.
__global__ __launch_bounds__(256) void k_attn_s(
    const u16* __restrict__ qkv, u16* __restrict__ o)
{
    const int wave = threadIdx.x >> 6, lane = threadIdx.x & 63;
    const int g = blockIdx.x * 4 + wave;          // 19968 groups
    const int t = g % 24, bf = g / 24, f = bf % 13, b = bf / 13;
    const int base = b * 624 + f * 24 + t;        // row stride 312
    const int h = lane >> 3, i = (lane >> 2) & 1, c = lane & 3;
    const int off = h * 64 + c * 16;

    float qf[16];
    load16f(qkv + (size_t)(base + i * 312) * 1536 + off, qf);

    float s[2];
#pragma unroll
    for (int j = 0; j < 2; ++j) {
        float d = dot16(qkv + (size_t)(base + j * 312) * 1536 + 512 + off, qf);
        d += __shfl_xor(d, 1);
        d += __shfl_xor(d, 2);
        s[j] = d * 0.125f;
    }
    const float m = fmaxf(s[0], s[1]);
    const float e0 = expf(s[0] - m), e1 = expf(s[1] - m);
    const float inv = 1.0f / (e0 + e1);
    const float p0 = e0 * inv, p1 = e1 * inv;

    float acc[16] = {};
    fma16(qkv + (size_t)base * 1536 + 1024 + off, p0, acc);
    fma16(qkv + (size_t)(base + 312) * 1536 + 1024 + off, p1, acc);

    store16(o + (size_t)(base + i * 312) * 512 + off, acc);
}

// Feature attn (L=13): one wave per (group, head). lane = i*4 + c.
// i = output row (13 of 16 valid), c = 16-dim chunk. Softmax fully in-lane.
__global__ __launch_bounds__(256) void k_attn_f(
    const u16* __restrict__ qkv, u16* __restrict__ o)
{
    const int wave = threadIdx.x >> 6, lane = threadIdx.x & 63;
    const int p = blockIdx.x * 4 + wave;          // 24576 (g,h)
    const int h = p & 7, g = p >> 3;
    const int t = g % 24, bs = g / 24, st = bs % 2, b = bs / 2;
    const int base = b * 624 + st * 312 + t;      // row stride 24
    const int i = lane >> 2, c = lane & 3;
    const int iq = (i < 13) ? i : 12;
    const int off = h * 64 + c * 16;

    float qf[16];
    load16f(qkv + (size_t)(base + iq * 24) * 1536 + off, qf);

    float sc[13];
#pragma unroll
    for (int j = 0; j < 13; ++j) {
        float d = dot16(qkv + (size_t)(base + j * 24) * 1536 + 512 + off, qf);
        d += __shfl_xor(d, 1);
        d += __shfl_xor(d, 2);
        sc[j] = d * 0.125f;
    }
    float m = sc[0];
#pragma unroll
    for (int j = 1; j < 13; ++j) m = fmaxf(m, sc[j]);
    float den = 0.0f;
#pragma unroll
    for (int j = 0; j < 13; ++j) { sc[j] = expf(sc[j] - m); den += sc[j]; }
    const float inv = 1.0f / den;

    float acc[16] = {};
#pragma unroll
    for (int j = 0; j < 13; ++j)
        fma16(qkv + (size_t)(base + j * 24) * 1536 + 1024 + off, sc[j], acc);
#pragma unroll
    for (int e = 0; e < 16; ++e) acc[e] *= inv;

    if (i < 13)
        store16(o + (size_t)(base + i * 24) * 512 + off, acc);
}

// ---------------------------------------------------------------- layernorm
template<bool OUTF32>
__global__ __launch_bounds__(256) void k_ln(
    const u16* __restrict__ in, const float* __restrict__ g,
    const float* __restrict__ be, u16* __restrict__ outb,
    float* __restrict__ outf)
{
    const int row  = blockIdx.x * 4 + (threadIdx.x >> 6);
    const int lane = threadIdx.x & 63;
    const u16* p = in + (size_t)row * 512 + lane * 8;

    uint4 va = *reinterpret_cast<const uint4*>(p);
    uint32_t ua[4] = { va.x, va.y, va.z, va.w };
    float x[8];
#pragma unroll
    for (int i = 0; i < 4; ++i) {
        x[2 * i]     = bf2f((u16)(ua[i] & 0xFFFFu));
        x[2 * i + 1] = bf2f((u16)(ua[i] >> 16));
    }
    float s = 0.f, sq = 0.f;
#pragma unroll
    for (int i = 0; i < 8; ++i) { s += x[i]; sq += x[i] * x[i]; }
#pragma unroll
    for (int off = 32; off; off >>= 1) {
        s  += __shfl_xor(s, off);
        sq += __shfl_xor(sq, off);
    }
    const float mean = s * (1.0f / 512.0f);
    const float var  = sq * (1.0f / 512.0f) - mean * mean;
    const float rstd = rsqrtf(var + 1e-5f);

    const int col = lane * 8;
    float4 g0 = *reinterpret_cast<const float4*>(g + col);
    float4 g1 = *reinterpret_cast<const float4*>(g + col + 4);
    float4 b0 = *reinterpret_cast<const float4*>(be + col);
    float4 b1 = *reinterpret_cast<const float4*>(be + col + 4);
    float gg[8] = { g0.x, g0.y, g0.z, g0.w, g1.x, g1.y, g1.z, g1.w };
    float bb[8] = { b0.x, b0.y, b0.z, b0.w, b1.x, b1.y, b1.z, b1.w };

    float y[8];
#pragma unroll
    for (int i = 0; i < 8; ++i) y[i] = (x[i] - mean) * rstd * gg[i] + bb[i];

    if (OUTF32) {
        float4 o0 = { y[0], y[1], y[2], y[3] };
        float4 o1 = { y[4], y[5], y[6], y[7] };
        reinterpret_cast<float4*>(outf + (size_t)row * 512 + col)[0] = o0;
        reinterpret_cast<float4*>(outf + (size_t)row * 512 + col + 4)[0] = o1;
    } else {
        uint32_t w[4];
#pragma unroll
        for (int i = 0; i < 4; ++i)
            w[i] = (uint32_t)f2bf(y[2 * i]) | ((uint32_t)f2bf(y[2 * i + 1]) << 16);
        uint4 ov = { w[0], w[1], w[2], w[3] };
        *reinterpret_cast<uint4*>(outb + (size_t)row * 512 + col) = ov;
    }
}

// ---------------------------------------------------------------- launch
extern "C" void kernel_launch(void* const* d_in, const int* in_sizes, int n_in,
                              void* d_out, int out_size, void* d_ws, size_t ws_size,
                              hipStream_t stream)
{
    const float* x       = (const float*)d_in[0];
    const float* w_in_s  = (const float*)d_in[1];
    const float* b_in_s  = (const float*)d_in[2];
    const float* w_out_s = (const float*)d_in[3];
    const float* b_out_s = (const float*)d_in[4];
    const float* w_in_f  = (const float*)d_in[5];
    const float* b_in_f  = (const float*)d_in[6];
    const float* w_out_f = (const float*)d_in[7];
    const float* b_out_f = (const float*)d_in[8];
    const float* w1      = (const float*)d_in[9];
    const float* b1      = (const float*)d_in[10];
    const float* w2      = (const float*)d_in[11];
    const float* b2      = (const float*)d_in[12];
    const float* g1      = (const float*)d_in[13];
    const float* be1     = (const float*)d_in[14];
    const float* g2      = (const float*)d_in[15];
    const float* be2     = (const float*)d_in[16];
    const float* g3      = (const float*)d_in[17];
    const float* be3     = (const float*)d_in[18];

    const int R = 39936;               // B*NS*NF*T
    u16* xb   = (u16*)d_ws;            // [R,512]  activation (bf16)
    u16* buf1 = xb + (size_t)R * 512;  // [R,2048] qkv(1536)+o(512) / ffn hidden
    u16* obuf = buf1 + (size_t)R * 1536;
    u16* wqs  = buf1 + (size_t)R * 2048;
    u16* wos  = wqs + 1536 * 512;
    u16* wqf  = wos + 512 * 512;
    u16* wof  = wqf + 1536 * 512;
    u16* w1b  = wof + 512 * 512;
    u16* w2b  = w1b + 2048 * 512;

    auto conv = [&](const float* src, u16* dst, int n) {
        int n4 = n / 4;
        k_f32_to_bf16<<<dim3((n4 + 255) / 256), dim3(256), 0, stream>>>(src, dst, n4);
    };
    conv(x,       xb,  R * 512);
    conv(w_in_s,  wqs, 1536 * 512);
    conv(w_out_s, wos, 512 * 512);
    conv(w_in_f,  wqf, 1536 * 512);
    conv(w_out_f, wof, 512 * 512);
    conv(w1,      w1b, 2048 * 512);
    conv(w2,      w2b, 512 * 2048);

    const dim3 blk(256);
    const int MT = R / 128;   // 312 row tiles

    // ---- station attention block ----
    k_gemm<false, false><<<dim3(12, MT), blk, 0, stream>>>(
        xb, wqs, b_in_s, nullptr, buf1, R, 1536, 512);
    k_attn_s<<<dim3(19968 / 4), blk, 0, stream>>>(buf1, obuf);
    k_gemm<false, true><<<dim3(4, MT), blk, 0, stream>>>(
        obuf, wos, b_out_s, xb, xb, R, 512, 512);
    k_ln<false><<<dim3(R / 4), blk, 0, stream>>>(xb, g1, be1, xb, nullptr);

    // ---- feature attention block ----
    k_gemm<false, false><<<dim3(12, MT), blk, 0, stream>>>(
        xb, wqf, b_in_f, nullptr, buf1, R, 1536, 512);
    k_attn_f<<<dim3(24576 / 4), blk, 0, stream>>>(buf1, obuf);
    k_gemm<false, true><<<dim3(4, MT), blk, 0, stream>>>(
        obuf, wof, b_out_f, xb, xb, R, 512, 512);
    k_ln<false><<<dim3(R / 4), blk, 0, stream>>>(xb, g2, be2, xb, nullptr);

    // ---- feed-forward ----
    k_gemm<true, false><<<dim3(16, MT), blk, 0, stream>>>(
        xb, w1b, b1, nullptr, buf1, R, 2048, 512);
    k_gemm<false, true><<<dim3(4, MT), blk, 0, stream>>>(
        buf1, w2b, b2, xb, xb, R, 512, 2048);
    k_ln<true><<<dim3(R / 4), blk, 0, stream>>>(xb, g3, be3, nullptr, (float*)d_out);
}

// Round 3
// 690.187 us; speedup vs baseline: 1.3704x; 1.0678x over previous
//
#include <hip/hip_runtime.h>
#include <stdint.h>

typedef unsigned short u16;
typedef __bf16 bf16x8 __attribute__((ext_vector_type(8)));
typedef float f32x4 __attribute__((ext_vector_type(4)));

#define DEV __device__ __forceinline__

DEV float bf2f(u16 u) {
    union { uint32_t u; float f; } c; c.u = ((uint32_t)u) << 16; return c.f;
}
DEV u16 f2bf(float f) {
    union { float f; uint32_t u; } c; c.f = f;
    uint32_t u = c.u;
    u += 0x7FFFu + ((u >> 16) & 1u);   // round-to-nearest-even
    return (u16)(u >> 16);
}

DEV void gload_lds16(const u16* gp, u16* lp) {
    __builtin_amdgcn_global_load_lds(
        (__attribute__((address_space(1))) u16*)(uintptr_t)gp,
        (__attribute__((address_space(3))) u16*)lp,
        16, 0, 0);
}

// ---- 16-bf16 (32B) helpers -------------------------------------------------
DEV void load16f(const u16* p, float* f) {
    uint4 a = *reinterpret_cast<const uint4*>(p);
    uint4 b = *reinterpret_cast<const uint4*>(p + 8);
    uint32_t w[8] = { a.x, a.y, a.z, a.w, b.x, b.y, b.z, b.w };
#pragma unroll
    for (int k = 0; k < 8; ++k) {
        union { uint32_t u; float f; } lo, hi;
        lo.u = w[k] << 16; hi.u = w[k] & 0xFFFF0000u;
        f[2 * k] = lo.f; f[2 * k + 1] = hi.f;
    }
}
DEV float dot16(const u16* p, const float* q) {
    uint4 a = *reinterpret_cast<const uint4*>(p);
    uint4 b = *reinterpret_cast<const uint4*>(p + 8);
    uint32_t w[8] = { a.x, a.y, a.z, a.w, b.x, b.y, b.z, b.w };
    float d = 0.0f;
#pragma unroll
    for (int k = 0; k < 8; ++k) {
        union { uint32_t u; float f; } lo, hi;
        lo.u = w[k] << 16; hi.u = w[k] & 0xFFFF0000u;
        d += q[2 * k] * lo.f;
        d += q[2 * k + 1] * hi.f;
    }
    return d;
}
DEV void fma16(const u16* p, float pw, float* acc) {
    uint4 a = *reinterpret_cast<const uint4*>(p);
    uint4 b = *reinterpret_cast<const uint4*>(p + 8);
    uint32_t w[8] = { a.x, a.y, a.z, a.w, b.x, b.y, b.z, b.w };
#pragma unroll
    for (int k = 0; k < 8; ++k) {
        union { uint32_t u; float f; } lo, hi;
        lo.u = w[k] << 16; hi.u = w[k] & 0xFFFF0000u;
        acc[2 * k] += pw * lo.f;
        acc[2 * k + 1] += pw * hi.f;
    }
}
DEV void store16(u16* p, const float* y) {
    uint32_t w[8];
#pragma unroll
    for (int k = 0; k < 8; ++k)
        w[k] = (uint32_t)f2bf(y[2 * k]) | ((uint32_t)f2bf(y[2 * k + 1]) << 16);
    uint4 a = { w[0], w[1], w[2], w[3] };
    uint4 b = { w[4], w[5], w[6], w[7] };
    *reinterpret_cast<uint4*>(p) = a;
    *reinterpret_cast<uint4*>(p + 8) = b;
}

// ---------------------------------------------------------------- convert
__global__ __launch_bounds__(256) void k_f32_to_bf16(
    const float* __restrict__ in, u16* __restrict__ out, int n4)
{
    int i = blockIdx.x * 256 + threadIdx.x;
    if (i >= n4) return;
    float4 v = reinterpret_cast<const float4*>(in)[i];
    ushort4 o;
    o.x = f2bf(v.x); o.y = f2bf(v.y); o.z = f2bf(v.z); o.w = f2bf(v.w);
    reinterpret_cast<ushort4*>(out)[i] = o;
}

// ---------------------------------------------------------------- GEMM
// C[M,N] = A[M,K] * W[N,K]^T + bias (+ residual) (+relu), all bf16 in, bf16 out.
// 128x128 tile, 4 waves (2x2). LDS tiles XOR-swizzled at 16B-chunk granularity:
// slot s holds (row = s>>2, global chunk = (s&3)^((s>>3)&3)); staged by
// pre-swizzling the per-lane GLOBAL chunk (LDS dest stays linear, rule #21).
// Grid is 1D, XCD-chunked: all N-tiles of one M-panel land on one XCD (T1).
template<bool RELU, bool RESID, int NT>
__global__ __launch_bounds__(256) void k_gemm(
    const u16* __restrict__ A, const u16* __restrict__ W,
    const float* __restrict__ bias, const u16* __restrict__ res,
    u16* __restrict__ C, int M, int N, int K)
{
    __shared__ __align__(16) u16 As[128 * 32];
    __shared__ __align__(16) u16 Bs[128 * 32];

    const int tid  = threadIdx.x;
    const int lane = tid & 63;
    const int wave = tid >> 6;
    const int wm   = wave >> 1;
    const int wn   = wave & 1;

    // XCD-aware block swizzle: 312 M-panels = 8 XCDs * 39 panels
    const int bid = blockIdx.x;            // 0 .. 312*NT-1
    const int xcd = bid & 7;
    const int j0  = bid >> 3;              // 0 .. 39*NT-1
    const long tileM = (long)(xcd * 39 + j0 / NT) * 128;
    const long tileN = (long)(j0 % NT) * 128;

    f32x4 acc[4][4] = {};

    // staging: row = tid>>2 (64 rows/half), chunk pre-swizzled within row
    const int r4 = tid >> 2;
    const int c8 = ((tid & 3) ^ ((tid >> 3) & 3)) * 8;
    const u16* Ab = A + (tileM + r4) * (long)K + c8;
    const u16* Wb = W + (tileN + r4) * (long)K + c8;
    u16* ldsA0 = As + wave * 512;
    u16* ldsA1 = As + 2048 + wave * 512;
    u16* ldsB0 = Bs + wave * 512;
    u16* ldsB1 = Bs + 2048 + wave * 512;

    const int arow = wm * 64 + (lane & 15);
    const int brow = wn * 64 + (lane & 15);
    // swizzled k-chunk offset: jc ^ ((row>>1)&3); row low bits == lane low bits
    const int koff = ((lane >> 4) ^ ((lane >> 1) & 3)) * 8;

    for (int kk = 0; kk < K; kk += 32) {
        gload_lds16(Ab + kk,                 ldsA0);
        gload_lds16(Ab + kk + (long)64 * K,  ldsA1);
        gload_lds16(Wb + kk,                 ldsB0);
        gload_lds16(Wb + kk + (long)64 * K,  ldsB1);
        __syncthreads();

        bf16x8 a[4], b[4];
#pragma unroll
        for (int f = 0; f < 4; ++f) {
            a[f] = *reinterpret_cast<const bf16x8*>(&As[(arow + f * 16) * 32 + koff]);
            b[f] = *reinterpret_cast<const bf16x8*>(&Bs[(brow + f * 16) * 32 + koff]);
        }
#pragma unroll
        for (int i = 0; i < 4; ++i)
#pragma unroll
            for (int j = 0; j < 4; ++j)
                acc[i][j] = __builtin_amdgcn_mfma_f32_16x16x32_bf16(
                    a[i], b[j], acc[i][j], 0, 0, 0);
        __syncthreads();
    }

    // epilogue: C/D layout col = lane&15, row = (lane>>4)*4 + reg
    const int crow = (int)tileM + wm * 64 + ((lane >> 4) << 2);
    const int ccol = (int)tileN + wn * 64 + (lane & 15);
#pragma unroll
    for (int i = 0; i < 4; ++i) {
#pragma unroll
        for (int j = 0; j < 4; ++j) {
            const int col = ccol + j * 16;
            const float bv = bias[col];
#pragma unroll
            for (int r = 0; r < 4; ++r) {
                const long row = crow + i * 16 + r;
                float v = acc[i][j][r] + bv;
                if (RESID) v += bf2f(res[row * N + col]);
                if (RELU)  v = fmaxf(v, 0.0f);
                C[row * N + col] = f2bf(v);
            }
        }
    }
}

// ---------------------------------------------------------------- attention
__global__ __launch_bounds__(256) void k_attn_s(
    const u16* __restrict__ qkv, u16* __restrict__ o)
{
    const int wave = threadIdx.x >> 6, lane = threadIdx.x & 63;
    const int g = blockIdx.x * 4 + wave;          // 19968 groups
    const int t = g % 24, bf = g / 24, f = bf % 13, b = bf / 13;
    const int base = b * 624 + f * 24 + t;        // row stride 312
    const int h = lane >> 3, i = (lane >> 2) & 1, c = lane & 3;
    const int off = h * 64 + c * 16;

    float qf[16];
    load16f(qkv + (size_t)(base + i * 312) * 1536 + off, qf);

    float s[2];
#pragma unroll
    for (int j = 0; j < 2; ++j) {
        float d = dot16(qkv + (size_t)(base + j * 312) * 1536 + 512 + off, qf);
        d += __shfl_xor(d, 1);
        d += __shfl_xor(d, 2);
        s[j] = d * 0.125f;
    }
    const float m = fmaxf(s[0], s[1]);
    const float e0 = expf(s[0] - m), e1 = expf(s[1] - m);
    const float inv = 1.0f / (e0 + e1);
    const float p0 = e0 * inv, p1 = e1 * inv;

    float acc[16] = {};
    fma16(qkv + (size_t)base * 1536 + 1024 + off, p0, acc);
    fma16(qkv + (size_t)(base + 312) * 1536 + 1024 + off, p1, acc);

    store16(o + (size_t)(base + i * 312) * 512 + off, acc);
}

__global__ __launch_bounds__(256) void k_attn_f(
    const u16* __restrict__ qkv, u16* __restrict__ o)
{
    const int wave = threadIdx.x >> 6, lane = threadIdx.x & 63;
    const int p = blockIdx.x * 4 + wave;          // 24576 (g,h)
    const int h = p & 7, g = p >> 3;
    const int t = g % 24, bs = g / 24, st = bs % 2, b = bs / 2;
    const int base = b * 624 + st * 312 + t;      // row stride 24
    const int i = lane >> 2, c = lane & 3;
    const int iq = (i < 13) ? i : 12;
    const int off = h * 64 + c * 16;

    float qf[16];
    load16f(qkv + (size_t)(base + iq * 24) * 1536 + off, qf);

    float sc[13];
#pragma unroll
    for (int j = 0; j < 13; ++j) {
        float d = dot16(qkv + (size_t)(base + j * 24) * 1536 + 512 + off, qf);
        d += __shfl_xor(d, 1);
        d += __shfl_xor(d, 2);
        sc[j] = d * 0.125f;
    }
    float m = sc[0];
#pragma unroll
    for (int j = 1; j < 13; ++j) m = fmaxf(m, sc[j]);
    float den = 0.0f;
#pragma unroll
    for (int j = 0; j < 13; ++j) { sc[j] = expf(sc[j] - m); den += sc[j]; }
    const float inv = 1.0f / den;

    float acc[16] = {};
#pragma unroll
    for (int j = 0; j < 13; ++j)
        fma16(qkv + (size_t)(base + j * 24) * 1536 + 1024 + off, sc[j], acc);
#pragma unroll
    for (int e = 0; e < 16; ++e) acc[e] *= inv;

    if (i < 13)
        store16(o + (size_t)(base + i * 24) * 512 + off, acc);
}

// ---------------------------------------------------------------- layernorm
template<bool OUTF32>
__global__ __launch_bounds__(256) void k_ln(
    const u16* __restrict__ in, const float* __restrict__ g,
    const float* __restrict__ be, u16* __restrict__ outb,
    float* __restrict__ outf)
{
    const int row  = blockIdx.x * 4 + (threadIdx.x >> 6);
    const int lane = threadIdx.x & 63;
    const u16* p = in + (size_t)row * 512 + lane * 8;

    uint4 va = *reinterpret_cast<const uint4*>(p);
    uint32_t ua[4] = { va.x, va.y, va.z, va.w };
    float x[8];
#pragma unroll
    for (int i = 0; i < 4; ++i) {
        x[2 * i]     = bf2f((u16)(ua[i] & 0xFFFFu));
        x[2 * i + 1] = bf2f((u16)(ua[i] >> 16));
    }
    float s = 0.f, sq = 0.f;
#pragma unroll
    for (int i = 0; i < 8; ++i) { s += x[i]; sq += x[i] * x[i]; }
#pragma unroll
    for (int off = 32; off; off >>= 1) {
        s  += __shfl_xor(s, off);
        sq += __shfl_xor(sq, off);
    }
    const float mean = s * (1.0f / 512.0f);
    const float var  = sq * (1.0f / 512.0f) - mean * mean;
    const float rstd = rsqrtf(var + 1e-5f);

    const int col = lane * 8;
    float4 g0 = *reinterpret_cast<const float4*>(g + col);
    float4 g1 = *reinterpret_cast<const float4*>(g + col + 4);
    float4 b0 = *reinterpret_cast<const float4*>(be + col);
    float4 b1 = *reinterpret_cast<const float4*>(be + col + 4);
    float gg[8] = { g0.x, g0.y, g0.z, g0.w, g1.x, g1.y, g1.z, g1.w };
    float bb[8] = { b0.x, b0.y, b0.z, b0.w, b1.x, b1.y, b1.z, b1.w };

    float y[8];
#pragma unroll
    for (int i = 0; i < 8; ++i) y[i] = (x[i] - mean) * rstd * gg[i] + bb[i];

    if (OUTF32) {
        float4 o0 = { y[0], y[1], y[2], y[3] };
        float4 o1 = { y[4], y[5], y[6], y[7] };
        reinterpret_cast<float4*>(outf + (size_t)row * 512 + col)[0] = o0;
        reinterpret_cast<float4*>(outf + (size_t)row * 512 + col + 4)[0] = o1;
    } else {
        uint32_t w[4];
#pragma unroll
        for (int i = 0; i < 4; ++i)
            w[i] = (uint32_t)f2bf(y[2 * i]) | ((uint32_t)f2bf(y[2 * i + 1]) << 16);
        uint4 ov = { w[0], w[1], w[2], w[3] };
        *reinterpret_cast<uint4*>(outb + (size_t)row * 512 + col) = ov;
    }
}

// ---------------------------------------------------------------- launch
extern "C" void kernel_launch(void* const* d_in, const int* in_sizes, int n_in,
                              void* d_out, int out_size, void* d_ws, size_t ws_size,
                              hipStream_t stream)
{
    const float* x       = (const float*)d_in[0];
    const float* w_in_s  = (const float*)d_in[1];
    const float* b_in_s  = (const float*)d_in[2];
    const float* w_out_s = (const float*)d_in[3];
    const float* b_out_s = (const float*)d_in[4];
    const float* w_in_f  = (const float*)d_in[5];
    const float* b_in_f  = (const float*)d_in[6];
    const float* w_out_f = (const float*)d_in[7];
    const float* b_out_f = (const float*)d_in[8];
    const float* w1      = (const float*)d_in[9];
    const float* b1      = (const float*)d_in[10];
    const float* w2      = (const float*)d_in[11];
    const float* b2      = (const float*)d_in[12];
    const float* g1      = (const float*)d_in[13];
    const float* be1     = (const float*)d_in[14];
    const float* g2      = (const float*)d_in[15];
    const float* be2     = (const float*)d_in[16];
    const float* g3      = (const float*)d_in[17];
    const float* be3     = (const float*)d_in[18];

    const int R = 39936;               // B*NS*NF*T
    u16* xb   = (u16*)d_ws;            // [R,512]  activation (bf16)
    u16* buf1 = xb + (size_t)R * 512;  // [R,2048] qkv(1536)+o(512) / ffn hidden
    u16* obuf = buf1 + (size_t)R * 1536;
    u16* wqs  = buf1 + (size_t)R * 2048;
    u16* wos  = wqs + 1536 * 512;
    u16* wqf  = wos + 512 * 512;
    u16* wof  = wqf + 1536 * 512;
    u16* w1b  = wof + 512 * 512;
    u16* w2b  = w1b + 2048 * 512;

    auto conv = [&](const float* src, u16* dst, int n) {
        int n4 = n / 4;
        k_f32_to_bf16<<<dim3((n4 + 255) / 256), dim3(256), 0, stream>>>(src, dst, n4);
    };
    conv(x,       xb,  R * 512);
    conv(w_in_s,  wqs, 1536 * 512);
    conv(w_out_s, wos, 512 * 512);
    conv(w_in_f,  wqf, 1536 * 512);
    conv(w_out_f, wof, 512 * 512);
    conv(w1,      w1b, 2048 * 512);
    conv(w2,      w2b, 512 * 2048);

    const dim3 blk(256);

    // ---- station attention block ----
    k_gemm<false, false, 12><<<dim3(312 * 12), blk, 0, stream>>>(
        xb, wqs, b_in_s, nullptr, buf1, R, 1536, 512);
    k_attn_s<<<dim3(19968 / 4), blk, 0, stream>>>(buf1, obuf);
    k_gemm<false, true, 4><<<dim3(312 * 4), blk, 0, stream>>>(
        obuf, wos, b_out_s, xb, xb, R, 512, 512);
    k_ln<false><<<dim3(R / 4), blk, 0, stream>>>(xb, g1, be1, xb, nullptr);

    // ---- feature attention block ----
    k_gemm<false, false, 12><<<dim3(312 * 12), blk, 0, stream>>>(
        xb, wqf, b_in_f, nullptr, buf1, R, 1536, 512);
    k_attn_f<<<dim3(24576 / 4), blk, 0, stream>>>(buf1, obuf);
    k_gemm<false, true, 4><<<dim3(312 * 4), blk, 0, stream>>>(
        obuf, wof, b_out_f, xb, xb, R, 512, 512);
    k_ln<false><<<dim3(R / 4), blk, 0, stream>>>(xb, g2, be2, xb, nullptr);

    // ---- feed-forward ----
    k_gemm<true, false, 16><<<dim3(312 * 16), blk, 0, stream>>>(
        xb, w1b, b1, nullptr, buf1, R, 2048, 512);
    k_gemm<false, true, 4><<<dim3(312 * 4), blk, 0, stream>>>(
        buf1, w2b, b2, xb, xb, R, 512, 2048);
    k_ln<true><<<dim3(R / 4), blk, 0, stream>>>(xb, g3, be3, nullptr, (float*)d_out);
}

// Round 4
// 672.974 us; speedup vs baseline: 1.4054x; 1.0256x over previous
//
#include <hip/hip_runtime.h>
#include <stdint.h>

typedef unsigned short u16;
typedef __bf16 bf16x8 __attribute__((ext_vector_type(8)));
typedef float f32x4 __attribute__((ext_vector_type(4)));

#define DEV __device__ __forceinline__

DEV float bf2f(u16 u) {
    union { uint32_t u; float f; } c; c.u = ((uint32_t)u) << 16; return c.f;
}
DEV u16 f2bf(float f) {
    union { float f; uint32_t u; } c; c.f = f;
    uint32_t u = c.u;
    u += 0x7FFFu + ((u >> 16) & 1u);   // round-to-nearest-even
    return (u16)(u >> 16);
}

DEV void gload_lds16(const u16* gp, u16* lp) {
    __builtin_amdgcn_global_load_lds(
        (__attribute__((address_space(1))) u16*)(uintptr_t)gp,
        (__attribute__((address_space(3))) u16*)lp,
        16, 0, 0);
}

// ---- 16-bf16 (32B) helpers -------------------------------------------------
DEV void load16f(const u16* p, float* f) {
    uint4 a = *reinterpret_cast<const uint4*>(p);
    uint4 b = *reinterpret_cast<const uint4*>(p + 8);
    uint32_t w[8] = { a.x, a.y, a.z, a.w, b.x, b.y, b.z, b.w };
#pragma unroll
    for (int k = 0; k < 8; ++k) {
        union { uint32_t u; float f; } lo, hi;
        lo.u = w[k] << 16; hi.u = w[k] & 0xFFFF0000u;
        f[2 * k] = lo.f; f[2 * k + 1] = hi.f;
    }
}
DEV float dot16(const u16* p, const float* q) {
    uint4 a = *reinterpret_cast<const uint4*>(p);
    uint4 b = *reinterpret_cast<const uint4*>(p + 8);
    uint32_t w[8] = { a.x, a.y, a.z, a.w, b.x, b.y, b.z, b.w };
    float d = 0.0f;
#pragma unroll
    for (int k = 0; k < 8; ++k) {
        union { uint32_t u; float f; } lo, hi;
        lo.u = w[k] << 16; hi.u = w[k] & 0xFFFF0000u;
        d += q[2 * k] * lo.f;
        d += q[2 * k + 1] * hi.f;
    }
    return d;
}
DEV void fma16(const u16* p, float pw, float* acc) {
    uint4 a = *reinterpret_cast<const uint4*>(p);
    uint4 b = *reinterpret_cast<const uint4*>(p + 8);
    uint32_t w[8] = { a.x, a.y, a.z, a.w, b.x, b.y, b.z, b.w };
#pragma unroll
    for (int k = 0; k < 8; ++k) {
        union { uint32_t u; float f; } lo, hi;
        lo.u = w[k] << 16; hi.u = w[k] & 0xFFFF0000u;
        acc[2 * k] += pw * lo.f;
        acc[2 * k + 1] += pw * hi.f;
    }
}
DEV void store16(u16* p, const float* y) {
    uint32_t w[8];
#pragma unroll
    for (int k = 0; k < 8; ++k)
        w[k] = (uint32_t)f2bf(y[2 * k]) | ((uint32_t)f2bf(y[2 * k + 1]) << 16);
    uint4 a = { w[0], w[1], w[2], w[3] };
    uint4 b = { w[4], w[5], w[6], w[7] };
    *reinterpret_cast<uint4*>(p) = a;
    *reinterpret_cast<uint4*>(p + 8) = b;
}

// ---------------------------------------------------------------- convert
__global__ __launch_bounds__(256) void k_f32_to_bf16(
    const float* __restrict__ in, u16* __restrict__ out, int n4)
{
    int i = blockIdx.x * 256 + threadIdx.x;
    if (i >= n4) return;
    float4 v = reinterpret_cast<const float4*>(in)[i];
    ushort4 o;
    o.x = f2bf(v.x); o.y = f2bf(v.y); o.z = f2bf(v.z); o.w = f2bf(v.w);
    reinterpret_cast<ushort4*>(out)[i] = o;
}

// ---------------------------------------------------------------- GEMM
// C[M,N] = A[M,K] * W[N,K]^T + bias (+ residual) (+relu), all bf16 in, bf16 out.
// 128x128 tile, 4 waves (2x2). 2-phase double-buffered pipeline (T3-minimum):
// prologue stages tile 0; each iter issues next-tile global_load_lds FIRST,
// then ds_read+MFMA on current buffer, then one vmcnt(0)+barrier per K-step.
// LDS 16B-chunk XOR swizzle (pre-swizzled global source, rule #21).
// Grid is 1D, XCD-chunked: all N-tiles of one M-panel land on one XCD (T1).
template<bool RELU, bool RESID, int NT>
__global__ __launch_bounds__(256) void k_gemm(
    const u16* __restrict__ A, const u16* __restrict__ W,
    const float* __restrict__ bias, const u16* __restrict__ res,
    u16* __restrict__ C, int M, int N, int K)
{
    __shared__ __align__(16) u16 As[2 * 128 * 32];
    __shared__ __align__(16) u16 Bs[2 * 128 * 32];

    const int tid  = threadIdx.x;
    const int lane = tid & 63;
    const int wave = tid >> 6;
    const int wm   = wave >> 1;
    const int wn   = wave & 1;

    // XCD-aware block swizzle: 312 M-panels = 8 XCDs * 39 panels
    const int bid = blockIdx.x;            // 0 .. 312*NT-1
    const int xcd = bid & 7;
    const int j0  = bid >> 3;              // 0 .. 39*NT-1
    const long tileM = (long)(xcd * 39 + j0 / NT) * 128;
    const long tileN = (long)(j0 % NT) * 128;

    f32x4 acc[4][4] = {};

    // staging: row = tid>>2 (64 rows/half), chunk pre-swizzled within row
    const int r4 = tid >> 2;
    const int c8 = ((tid & 3) ^ ((tid >> 3) & 3)) * 8;
    const u16* Ab = A + (tileM + r4) * (long)K + c8;
    const u16* Wb = W + (tileN + r4) * (long)K + c8;
    const int dst0 = wave * 512;           // within one 4096-elem buffer

    const int arow = wm * 64 + (lane & 15);
    const int brow = wn * 64 + (lane & 15);
    // swizzled k-chunk offset: jc ^ ((row>>1)&3); row low bits == lane low bits
    const int koff = ((lane >> 4) ^ ((lane >> 1) & 3)) * 8;

    auto stage = [&](int buf, int kk) {
        u16* a0 = As + buf * 4096 + dst0;
        u16* b0 = Bs + buf * 4096 + dst0;
        gload_lds16(Ab + kk,                a0);
        gload_lds16(Ab + kk + (long)64 * K, a0 + 2048);
        gload_lds16(Wb + kk,                b0);
        gload_lds16(Wb + kk + (long)64 * K, b0 + 2048);
    };
    auto compute = [&](int buf) {
        const u16* ab = As + buf * 4096;
        const u16* bb = Bs + buf * 4096;
        bf16x8 a[4], b[4];
#pragma unroll
        for (int f = 0; f < 4; ++f) {
            a[f] = *reinterpret_cast<const bf16x8*>(&ab[(arow + f * 16) * 32 + koff]);
            b[f] = *reinterpret_cast<const bf16x8*>(&bb[(brow + f * 16) * 32 + koff]);
        }
#pragma unroll
        for (int i = 0; i < 4; ++i)
#pragma unroll
            for (int j = 0; j < 4; ++j)
                acc[i][j] = __builtin_amdgcn_mfma_f32_16x16x32_bf16(
                    a[i], b[j], acc[i][j], 0, 0, 0);
    };

    // prologue
    stage(0, 0);
    __syncthreads();

    int cur = 0;
    for (int kk = 0; kk < K - 32; kk += 32) {
        stage(cur ^ 1, kk + 32);   // issue next-tile loads BEFORE compute
        compute(cur);
        __syncthreads();           // drains vmcnt(0)+lgkmcnt(0): next buf ready
        cur ^= 1;
    }
    compute(cur);                  // last tile, no prefetch

    // epilogue: C/D layout col = lane&15, row = (lane>>4)*4 + reg
    const int crow = (int)tileM + wm * 64 + ((lane >> 4) << 2);
    const int ccol = (int)tileN + wn * 64 + (lane & 15);
#pragma unroll
    for (int i = 0; i < 4; ++i) {
#pragma unroll
        for (int j = 0; j < 4; ++j) {
            const int col = ccol + j * 16;
            const float bv = bias[col];
#pragma unroll
            for (int r = 0; r < 4; ++r) {
                const long row = crow + i * 16 + r;
                float v = acc[i][j][r] + bv;
                if (RESID) v += bf2f(res[row * N + col]);
                if (RELU)  v = fmaxf(v, 0.0f);
                C[row * N + col] = f2bf(v);
            }
        }
    }
}

// ---------------------------------------------------------------- attention
__global__ __launch_bounds__(256) void k_attn_s(
    const u16* __restrict__ qkv, u16* __restrict__ o)
{
    const int wave = threadIdx.x >> 6, lane = threadIdx.x & 63;
    const int g = blockIdx.x * 4 + wave;          // 19968 groups
    const int t = g % 24, bf = g / 24, f = bf % 13, b = bf / 13;
    const int base = b * 624 + f * 24 + t;        // row stride 312
    const int h = lane >> 3, i = (lane >> 2) & 1, c = lane & 3;
    const int off = h * 64 + c * 16;

    float qf[16];
    load16f(qkv + (size_t)(base + i * 312) * 1536 + off, qf);

    float s[2];
#pragma unroll
    for (int j = 0; j < 2; ++j) {
        float d = dot16(qkv + (size_t)(base + j * 312) * 1536 + 512 + off, qf);
        d += __shfl_xor(d, 1);
        d += __shfl_xor(d, 2);
        s[j] = d * 0.125f;
    }
    const float m = fmaxf(s[0], s[1]);
    const float e0 = expf(s[0] - m), e1 = expf(s[1] - m);
    const float inv = 1.0f / (e0 + e1);
    const float p0 = e0 * inv, p1 = e1 * inv;

    float acc[16] = {};
    fma16(qkv + (size_t)base * 1536 + 1024 + off, p0, acc);
    fma16(qkv + (size_t)(base + 312) * 1536 + 1024 + off, p1, acc);

    store16(o + (size_t)(base + i * 312) * 512 + off, acc);
}

__global__ __launch_bounds__(256) void k_attn_f(
    const u16* __restrict__ qkv, u16* __restrict__ o)
{
    const int wave = threadIdx.x >> 6, lane = threadIdx.x & 63;
    const int p = blockIdx.x * 4 + wave;          // 24576 (g,h)
    const int h = p & 7, g = p >> 3;
    const int t = g % 24, bs = g / 24, st = bs % 2, b = bs / 2;
    const int base = b * 624 + st * 312 + t;      // row stride 24
    const int i = lane >> 2, c = lane & 3;
    const int iq = (i < 13) ? i : 12;
    const int off = h * 64 + c * 16;

    float qf[16];
    load16f(qkv + (size_t)(base + iq * 24) * 1536 + off, qf);

    float sc[13];
#pragma unroll
    for (int j = 0; j < 13; ++j) {
        float d = dot16(qkv + (size_t)(base + j * 24) * 1536 + 512 + off, qf);
        d += __shfl_xor(d, 1);
        d += __shfl_xor(d, 2);
        sc[j] = d * 0.125f;
    }
    float m = sc[0];
#pragma unroll
    for (int j = 1; j < 13; ++j) m = fmaxf(m, sc[j]);
    float den = 0.0f;
#pragma unroll
    for (int j = 0; j < 13; ++j) { sc[j] = expf(sc[j] - m); den += sc[j]; }
    const float inv = 1.0f / den;

    float acc[16] = {};
#pragma unroll
    for (int j = 0; j < 13; ++j)
        fma16(qkv + (size_t)(base + j * 24) * 1536 + 1024 + off, sc[j], acc);
#pragma unroll
    for (int e = 0; e < 16; ++e) acc[e] *= inv;

    if (i < 13)
        store16(o + (size_t)(base + i * 24) * 512 + off, acc);
}

// ---------------------------------------------------------------- layernorm
template<bool OUTF32>
__global__ __launch_bounds__(256) void k_ln(
    const u16* __restrict__ in, const float* __restrict__ g,
    const float* __restrict__ be, u16* __restrict__ outb,
    float* __restrict__ outf)
{
    const int row  = blockIdx.x * 4 + (threadIdx.x >> 6);
    const int lane = threadIdx.x & 63;
    const u16* p = in + (size_t)row * 512 + lane * 8;

    uint4 va = *reinterpret_cast<const uint4*>(p);
    uint32_t ua[4] = { va.x, va.y, va.z, va.w };
    float x[8];
#pragma unroll
    for (int i = 0; i < 4; ++i) {
        x[2 * i]     = bf2f((u16)(ua[i] & 0xFFFFu));
        x[2 * i + 1] = bf2f((u16)(ua[i] >> 16));
    }
    float s = 0.f, sq = 0.f;
#pragma unroll
    for (int i = 0; i < 8; ++i) { s += x[i]; sq += x[i] * x[i]; }
#pragma unroll
    for (int off = 32; off; off >>= 1) {
        s  += __shfl_xor(s, off);
        sq += __shfl_xor(sq, off);
    }
    const float mean = s * (1.0f / 512.0f);
    const float var  = sq * (1.0f / 512.0f) - mean * mean;
    const float rstd = rsqrtf(var + 1e-5f);

    const int col = lane * 8;
    float4 g0 = *reinterpret_cast<const float4*>(g + col);
    float4 g1 = *reinterpret_cast<const float4*>(g + col + 4);
    float4 b0 = *reinterpret_cast<const float4*>(be + col);
    float4 b1 = *reinterpret_cast<const float4*>(be + col + 4);
    float gg[8] = { g0.x, g0.y, g0.z, g0.w, g1.x, g1.y, g1.z, g1.w };
    float bb[8] = { b0.x, b0.y, b0.z, b0.w, b1.x, b1.y, b1.z, b1.w };

    float y[8];
#pragma unroll
    for (int i = 0; i < 8; ++i) y[i] = (x[i] - mean) * rstd * gg[i] + bb[i];

    if (OUTF32) {
        float4 o0 = { y[0], y[1], y[2], y[3] };
        float4 o1 = { y[4], y[5], y[6], y[7] };
        reinterpret_cast<float4*>(outf + (size_t)row * 512 + col)[0] = o0;
        reinterpret_cast<float4*>(outf + (size_t)row * 512 + col + 4)[0] = o1;
    } else {
        uint32_t w[4];
#pragma unroll
        for (int i = 0; i < 4; ++i)
            w[i] = (uint32_t)f2bf(y[2 * i]) | ((uint32_t)f2bf(y[2 * i + 1]) << 16);
        uint4 ov = { w[0], w[1], w[2], w[3] };
        *reinterpret_cast<uint4*>(outb + (size_t)row * 512 + col) = ov;
    }
}

// ---------------------------------------------------------------- launch
extern "C" void kernel_launch(void* const* d_in, const int* in_sizes, int n_in,
                              void* d_out, int out_size, void* d_ws, size_t ws_size,
                              hipStream_t stream)
{
    const float* x       = (const float*)d_in[0];
    const float* w_in_s  = (const float*)d_in[1];
    const float* b_in_s  = (const float*)d_in[2];
    const float* w_out_s = (const float*)d_in[3];
    const float* b_out_s = (const float*)d_in[4];
    const float* w_in_f  = (const float*)d_in[5];
    const float* b_in_f  = (const float*)d_in[6];
    const float* w_out_f = (const float*)d_in[7];
    const float* b_out_f = (const float*)d_in[8];
    const float* w1      = (const float*)d_in[9];
    const float* b1      = (const float*)d_in[10];
    const float* w2      = (const float*)d_in[11];
    const float* b2      = (const float*)d_in[12];
    const float* g1      = (const float*)d_in[13];
    const float* be1     = (const float*)d_in[14];
    const float* g2      = (const float*)d_in[15];
    const float* be2     = (const float*)d_in[16];
    const float* g3      = (const float*)d_in[17];
    const float* be3     = (const float*)d_in[18];

    const int R = 39936;               // B*NS*NF*T
    u16* xb   = (u16*)d_ws;            // [R,512]  activation (bf16)
    u16* buf1 = xb + (size_t)R * 512;  // [R,2048] qkv(1536)+o(512) / ffn hidden
    u16* obuf = buf1 + (size_t)R * 1536;
    u16* wqs  = buf1 + (size_t)R * 2048;
    u16* wos  = wqs + 1536 * 512;
    u16* wqf  = wos + 512 * 512;
    u16* wof  = wqf + 1536 * 512;
    u16* w1b  = wof + 512 * 512;
    u16* w2b  = w1b + 2048 * 512;

    auto conv = [&](const float* src, u16* dst, int n) {
        int n4 = n / 4;
        k_f32_to_bf16<<<dim3((n4 + 255) / 256), dim3(256), 0, stream>>>(src, dst, n4);
    };
    conv(x,       xb,  R * 512);
    conv(w_in_s,  wqs, 1536 * 512);
    conv(w_out_s, wos, 512 * 512);
    conv(w_in_f,  wqf, 1536 * 512);
    conv(w_out_f, wof, 512 * 512);
    conv(w1,      w1b, 2048 * 512);
    conv(w2,      w2b, 512 * 2048);

    const dim3 blk(256);

    // ---- station attention block ----
    k_gemm<false, false, 12><<<dim3(312 * 12), blk, 0, stream>>>(
        xb, wqs, b_in_s, nullptr, buf1, R, 1536, 512);
    k_attn_s<<<dim3(19968 / 4), blk, 0, stream>>>(buf1, obuf);
    k_gemm<false, true, 4><<<dim3(312 * 4), blk, 0, stream>>>(
        obuf, wos, b_out_s, xb, xb, R, 512, 512);
    k_ln<false><<<dim3(R / 4), blk, 0, stream>>>(xb, g1, be1, xb, nullptr);

    // ---- feature attention block ----
    k_gemm<false, false, 12><<<dim3(312 * 12), blk, 0, stream>>>(
        xb, wqf, b_in_f, nullptr, buf1, R, 1536, 512);
    k_attn_f<<<dim3(24576 / 4), blk, 0, stream>>>(buf1, obuf);
    k_gemm<false, true, 4><<<dim3(312 * 4), blk, 0, stream>>>(
        obuf, wof, b_out_f, xb, xb, R, 512, 512);
    k_ln<false><<<dim3(R / 4), blk, 0, stream>>>(xb, g2, be2, xb, nullptr);

    // ---- feed-forward ----
    k_gemm<true, false, 16><<<dim3(312 * 16), blk, 0, stream>>>(
        xb, w1b, b1, nullptr, buf1, R, 2048, 512);
    k_gemm<false, true, 4><<<dim3(312 * 4), blk, 0, stream>>>(
        buf1, w2b, b2, xb, xb, R, 512, 2048);
    k_ln<true><<<dim3(R / 4), blk, 0, stream>>>(xb, g3, be3, nullptr, (float*)d_out);
}